// Round 1
// baseline (807.205 us; speedup 1.0000x reference)
//
#include <hip/hip_runtime.h>

#define LBL 256

__global__ void hist_kernel(const int* __restrict__ pred, const int* __restrict__ gt,
                            int* __restrict__ C, int n4, int n) {
    int idx = blockIdx.x * blockDim.x + threadIdx.x;
    int stride = gridDim.x * blockDim.x;
    const int4* p4 = (const int4*)pred;
    const int4* g4 = (const int4*)gt;
    for (int i = idx; i < n4; i += stride) {
        int4 p = p4[i];
        int4 g = g4[i];
        atomicAdd(&C[(g.x << 8) + p.x], 1);
        atomicAdd(&C[(g.y << 8) + p.y], 1);
        atomicAdd(&C[(g.z << 8) + p.z], 1);
        atomicAdd(&C[(g.w << 8) + p.w], 1);
    }
    // tail (n not multiple of 4) — n==4096*4096 here so this is dead, kept for safety
    if (idx == 0) {
        for (int i = n4 * 4; i < n; ++i) atomicAdd(&C[(gt[i] << 8) + pred[i]], 1);
    }
}

__global__ void finalize_kernel(const int* __restrict__ C, float* __restrict__ out) {
    __shared__ int gt_size[LBL], pred_size[LBL], best_p[LBL], inter_s[LBL];
    __shared__ int row_pairs_s[LBL], col_cnt_s[LBL];
    __shared__ unsigned char has_s[LBL], used_s[LBL];
    int t = threadIdx.x;

    // full row sum (includes background column p=0) -> gt_size
    int gs = 0;
    #pragma unroll 16
    for (int p = 0; p < LBL; ++p) gs += C[t * LBL + p];
    gt_size[t] = gs;

    // full column sum (includes background row g=0) -> pred_size
    int ps = 0;
    #pragma unroll 16
    for (int g = 0; g < LBL; ++g) ps += C[g * LBL + t];
    pred_size[t] = ps;

    // per-gt-row scan over Cnz (g>=1, p>=1): overlap count, majority match.
    // 2*c > gt_size can hold for at most one p, so first hit == argmax.
    int rp = 0, bp = 0, it = 0;
    bool hs = false;
    if (t >= 1) {
        #pragma unroll 8
        for (int p = 1; p < LBL; ++p) {
            int c = C[t * LBL + p];
            if (c > 0) rp++;
            if (!hs && 2 * c > gs) { hs = true; bp = p; it = c; }
        }
    }
    row_pairs_s[t] = rp;
    best_p[t] = bp;          // 0 when no match (matches jnp argmax of all-false)
    inter_s[t] = it;         // 0 when no match (Cnz[g,0]==0)
    has_s[t] = hs ? 1 : 0;

    // per-pred-column overlap count over Cnz
    int cc = 0;
    if (t >= 1) {
        #pragma unroll 8
        for (int g = 1; g < LBL; ++g) if (C[g * LBL + t] > 0) cc++;
    }
    col_cnt_s[t] = cc;
    used_s[t] = 0;
    __syncthreads();

    if (t == 0) {
        int num_gt = 0, num_pred = 0, pairs = 0, ea = 0;
        for (int i = 1; i < LBL; ++i) {
            if (gt_size[i] > 0) num_gt++;
            if (pred_size[i] > 0) num_pred++;
            pairs += row_pairs_s[i];
            if (col_cnt_s[i] > 1) ea++;
        }
        // greedy matching, ascending gt label; each pred usable once
        int tp = 0;
        float seg_sum = 0.0f;
        for (int gl = 1; gl < LBL; ++gl) {
            int pl = best_p[gl];
            bool ok = has_s[gl] && !used_s[pl];
            if (ok) {
                int uni = gt_size[gl] + pred_size[pl] - inter_s[gl];
                if (uni < 1) uni = 1;
                float iou = (float)inter_s[gl] / (float)uni;
                seg_sum += iou;
                used_s[pl] = 1;
                tp++;
            }
        }
        float ng = (float)(num_gt >= 1 ? num_gt : 1);
        float seg = seg_sum / ng;
        int ns = pairs - tp;
        int fn = num_gt - tp;
        int fp_ = num_pred - tp;
        float det = 1.0f - (float)(fp_ + fn + ns + ea) / ng;
        bool both_empty = (num_gt == 0) && (num_pred == 0);
        bool any_empty = (num_gt == 0) || (num_pred == 0);
        if (both_empty) { seg = 1.0f; det = 1.0f; }
        else if (any_empty) { seg = 0.0f; det = 0.0f; }
        out[0] = seg;
        out[1] = det;
    }
}

extern "C" void kernel_launch(void* const* d_in, const int* in_sizes, int n_in,
                              void* d_out, int out_size, void* d_ws, size_t ws_size,
                              hipStream_t stream) {
    const int* pred = (const int*)d_in[0];
    const int* gt = (const int*)d_in[1];
    float* out = (float*)d_out;
    int* C = (int*)d_ws;              // 256*256*4 = 256 KB of scratch
    int n = in_sizes[0];
    int n4 = n / 4;

    hipMemsetAsync(C, 0, LBL * LBL * sizeof(int), stream);

    int threads = 256;
    int blocks = 2048;                 // 512K threads, 8 int4 iters each at n=16.7M
    hist_kernel<<<blocks, threads, 0, stream>>>(pred, gt, C, n4, n);
    finalize_kernel<<<1, 256, 0, stream>>>(C, out);
}

// Round 2
// 222.973 us; speedup vs baseline: 3.6202x; 3.6202x over previous
//
#include <hip/hip_runtime.h>

#define LBL 256
#define NBINS (LBL * LBL)      // 65536 bins
#define NWORDS (NBINS / 2)     // 32768 packed u32 words (2 x u16 counters)
#define HIST_BLOCKS 256
#define HIST_THREADS 1024
#define RED_THREADS 256
#define RED_BLOCKS (NWORDS / 4 / RED_THREADS)  // 32

// ---------------- histogram with LDS privatization (packed u16 pairs) -------
// 128 KB static LDS -> 1 block/CU on gfx950 (160 KB/CU). Each block sees
// <= 65536 pixels, so a packed 16-bit half-counter cannot overflow into its
// neighbor (per-bin per-block counts ~10 with these inputs, hard limit 65535).
__global__ __launch_bounds__(HIST_THREADS, 1)
void hist_priv_kernel(const int* __restrict__ pred, const int* __restrict__ gt,
                      unsigned int* __restrict__ partial, int n4, int n) {
    __shared__ unsigned int h[NWORDS];  // 128 KB
    const int t = threadIdx.x;
    #pragma unroll
    for (int i = t; i < NWORDS; i += HIST_THREADS) h[i] = 0u;
    __syncthreads();

    const int4* p4 = (const int4*)pred;
    const int4* g4 = (const int4*)gt;
    const int stride = HIST_BLOCKS * HIST_THREADS;
    for (int i = blockIdx.x * HIST_THREADS + t; i < n4; i += stride) {
        int4 p = p4[i];
        int4 g = g4[i];
        int b0 = (g.x << 8) | p.x;
        int b1 = (g.y << 8) | p.y;
        int b2 = (g.z << 8) | p.z;
        int b3 = (g.w << 8) | p.w;
        atomicAdd(&h[b0 >> 1], 1u << ((b0 & 1) << 4));
        atomicAdd(&h[b1 >> 1], 1u << ((b1 & 1) << 4));
        atomicAdd(&h[b2 >> 1], 1u << ((b2 & 1) << 4));
        atomicAdd(&h[b3 >> 1], 1u << ((b3 & 1) << 4));
    }
    // tail (n % 4 != 0) — dead for 4096x4096, kept for safety
    if (blockIdx.x == 0 && t == 0) {
        for (int i = n4 * 4; i < n; ++i) {
            int b = (gt[i] << 8) | pred[i];
            atomicAdd(&h[b >> 1], 1u << ((b & 1) << 4));
        }
    }
    __syncthreads();
    // non-atomic flush of the packed image to this block's private slice
    uint4* dst = (uint4*)(partial + (size_t)blockIdx.x * NWORDS);
    const uint4* src = (const uint4*)h;
    #pragma unroll
    for (int i = t; i < NWORDS / 4; i += HIST_THREADS) dst[i] = src[i];
}

// ---------------- reduce 256 packed partials -> final C ---------------------
__global__ __launch_bounds__(RED_THREADS)
void reduce_kernel(const unsigned int* __restrict__ partial, int* __restrict__ C) {
    const int t = blockIdx.x * RED_THREADS + threadIdx.x;  // 0..8191, 4 words = 8 bins each
    const uint4* p4 = (const uint4*)partial;
    int s0 = 0, s1 = 0, s2 = 0, s3 = 0, s4 = 0, s5 = 0, s6 = 0, s7 = 0;
    #pragma unroll 8
    for (int b = 0; b < HIST_BLOCKS; ++b) {
        uint4 v = p4[(size_t)b * (NWORDS / 4) + t];
        s0 += (int)(v.x & 0xFFFFu); s1 += (int)(v.x >> 16);
        s2 += (int)(v.y & 0xFFFFu); s3 += (int)(v.y >> 16);
        s4 += (int)(v.z & 0xFFFFu); s5 += (int)(v.z >> 16);
        s6 += (int)(v.w & 0xFFFFu); s7 += (int)(v.w >> 16);
    }
    int4* Co = (int4*)C;
    Co[2 * t]     = make_int4(s0, s1, s2, s3);
    Co[2 * t + 1] = make_int4(s4, s5, s6, s7);
}

// ---------------- fallback histogram (direct device atomics) ----------------
__global__ void hist_atomic_kernel(const int* __restrict__ pred, const int* __restrict__ gt,
                                   int* __restrict__ C, int n4, int n) {
    int idx = blockIdx.x * blockDim.x + threadIdx.x;
    int stride = gridDim.x * blockDim.x;
    const int4* p4 = (const int4*)pred;
    const int4* g4 = (const int4*)gt;
    for (int i = idx; i < n4; i += stride) {
        int4 p = p4[i];
        int4 g = g4[i];
        atomicAdd(&C[(g.x << 8) + p.x], 1);
        atomicAdd(&C[(g.y << 8) + p.y], 1);
        atomicAdd(&C[(g.z << 8) + p.z], 1);
        atomicAdd(&C[(g.w << 8) + p.w], 1);
    }
    if (idx == 0) {
        for (int i = n4 * 4; i < n; ++i) atomicAdd(&C[(gt[i] << 8) + pred[i]], 1);
    }
}

// ---------------- finalize: SEG/DET from the 256x256 confusion matrix -------
__global__ __launch_bounds__(1024)
void finalize_kernel(const int* __restrict__ C, float* __restrict__ out) {
    __shared__ int scratch[1024];
    __shared__ int gt_size[LBL], pred_size[LBL];
    __shared__ int best_p[LBL], inter_s[LBL], colcnt[LBL];
    __shared__ unsigned char has_s[LBL], used_s[LBL];
    __shared__ int s_pairs, s_ngt, s_npred, s_ea;

    const int t = threadIdx.x;
    if (t == 0) { s_pairs = 0; s_ngt = 0; s_npred = 0; s_ea = 0; }
    if (t < LBL) { best_p[t] = 0; inter_s[t] = 0; colcnt[t] = 0; has_s[t] = 0; used_s[t] = 0; }

    const int4* C4 = (const int4*)C;
    const int r = t >> 2, q = t & 3;  // 4 threads per row, 64 cols each

    // phase 1: full row sums (includes background column) -> gt_size
    int s = 0;
    #pragma unroll
    for (int j = 0; j < 16; ++j) {
        int4 v = C4[r * 64 + q * 16 + j];
        s += v.x + v.y + v.z + v.w;
    }
    scratch[t] = s;
    __syncthreads();
    if (t < LBL)
        gt_size[t] = scratch[4 * t] + scratch[4 * t + 1] + scratch[4 * t + 2] + scratch[4 * t + 3];
    __syncthreads();

    // phase 2: full col sums (includes background row) + per-col overlap counts on Cnz
    {
        const int c = t & 255, q2 = t >> 8;  // 4 threads per col, 64 rows each
        int cs = 0, cc = 0;
        #pragma unroll 8
        for (int g0 = 0; g0 < 64; ++g0) {
            int row = q2 * 64 + g0;
            int v = C[row * LBL + c];  // coalesced across c
            cs += v;
            cc += (row >= 1 && c >= 1 && v > 0) ? 1 : 0;
        }
        scratch[t] = cs;
        if (cc) atomicAdd(&colcnt[c], cc);
    }

    // phase 3: per-row scan on Cnz (needs gt_size): pair count + majority match.
    // 2*c > gt_size can hold for at most one p per row -> single writer per row.
    if (r >= 1) {
        const int gs = gt_size[r];
        int rp = 0;
        #pragma unroll
        for (int j = 0; j < 16; ++j) {
            int4 v = C4[r * 64 + q * 16 + j];
            int cb = q * 64 + 4 * j;
            if (cb >= 1) {  // col 0 excluded from Cnz
                if (v.x > 0) rp++;
                if (2 * v.x > gs) { has_s[r] = 1; best_p[r] = cb; inter_s[r] = v.x; }
            }
            if (v.y > 0) rp++;
            if (2 * v.y > gs) { has_s[r] = 1; best_p[r] = cb + 1; inter_s[r] = v.y; }
            if (v.z > 0) rp++;
            if (2 * v.z > gs) { has_s[r] = 1; best_p[r] = cb + 2; inter_s[r] = v.z; }
            if (v.w > 0) rp++;
            if (2 * v.w > gs) { has_s[r] = 1; best_p[r] = cb + 3; inter_s[r] = v.w; }
        }
        if (rp) atomicAdd(&s_pairs, rp);
    }
    __syncthreads();

    if (t < LBL)
        pred_size[t] = scratch[t] + scratch[256 + t] + scratch[512 + t] + scratch[768 + t];
    __syncthreads();

    if (t >= 1 && t < LBL) {
        if (gt_size[t] > 0) atomicAdd(&s_ngt, 1);
        if (pred_size[t] > 0) atomicAdd(&s_npred, 1);
        if (colcnt[t] > 1) atomicAdd(&s_ea, 1);
    }
    __syncthreads();

    if (t == 0) {
        const int num_gt = s_ngt, num_pred = s_npred, pairs = s_pairs, ea = s_ea;
        int tp = 0;
        float seg_sum = 0.0f;
        // greedy matching in ascending gt-label order; a pred may match once
        for (int gl = 1; gl < LBL; ++gl) {
            if (has_s[gl]) {
                int pl = best_p[gl];
                if (!used_s[pl]) {
                    int uni = gt_size[gl] + pred_size[pl] - inter_s[gl];
                    if (uni < 1) uni = 1;
                    seg_sum += (float)inter_s[gl] / (float)uni;
                    used_s[pl] = 1;
                    tp++;
                }
            }
        }
        float ng = (float)(num_gt >= 1 ? num_gt : 1);
        float seg = seg_sum / ng;
        int ns = pairs - tp;
        int fn = num_gt - tp;
        int fp_ = num_pred - tp;
        float det = 1.0f - (float)(fp_ + fn + ns + ea) / ng;
        bool both_empty = (num_gt == 0) && (num_pred == 0);
        bool any_empty = (num_gt == 0) || (num_pred == 0);
        if (both_empty) { seg = 1.0f; det = 1.0f; }
        else if (any_empty) { seg = 0.0f; det = 0.0f; }
        out[0] = seg;
        out[1] = det;
    }
}

extern "C" void kernel_launch(void* const* d_in, const int* in_sizes, int n_in,
                              void* d_out, int out_size, void* d_ws, size_t ws_size,
                              hipStream_t stream) {
    const int* pred = (const int*)d_in[0];
    const int* gt = (const int*)d_in[1];
    float* out = (float*)d_out;
    const int n = in_sizes[0];
    const int n4 = n / 4;

    const size_t part_bytes = (size_t)HIST_BLOCKS * NWORDS * sizeof(unsigned int);  // 32 MB
    const size_t need = part_bytes + (size_t)NBINS * sizeof(int);

    if (ws_size >= need) {
        unsigned int* partial = (unsigned int*)d_ws;
        int* C = (int*)((char*)d_ws + part_bytes);
        hist_priv_kernel<<<HIST_BLOCKS, HIST_THREADS, 0, stream>>>(pred, gt, partial, n4, n);
        reduce_kernel<<<RED_BLOCKS, RED_THREADS, 0, stream>>>(partial, C);
        finalize_kernel<<<1, 1024, 0, stream>>>(C, out);
    } else {
        // fallback: direct device-scope atomics (slow but correct)
        int* C = (int*)d_ws;
        hipMemsetAsync(C, 0, NBINS * sizeof(int), stream);
        hist_atomic_kernel<<<2048, 256, 0, stream>>>(pred, gt, C, n4, n);
        finalize_kernel<<<1, 1024, 0, stream>>>(C, out);
    }
}

// Round 4
// 169.506 us; speedup vs baseline: 4.7621x; 1.3154x over previous
//
#include <hip/hip_runtime.h>

#define LBL 256
#define NBINS (LBL * LBL)      // 65536 bins
#define NWORDS (NBINS / 2)     // 32768 packed u32 words (2 x u16 counters)
#define NQUADS (NWORDS / 4)    // 8192 uint4 quads (8 bins each)
#define HIST_BLOCKS 256
#define HIST_THREADS 1024

typedef int vint4 __attribute__((ext_vector_type(4)));  // native vec for nontemporal builtins

// ---------------- histogram with LDS privatization (packed u16 pairs) -------
// 128 KB static LDS -> 1 block/CU (160 KB/CU). Each block sees <= 65536
// pixels, so a packed 16-bit half cannot overflow (per-bin/block ~10 here).
// Unroll x4: 8 independent nontemporal 16B loads in flight per thread to
// cover ~900-cycle HBM latency at 16 waves/CU.
__global__ __launch_bounds__(HIST_THREADS, 4)
void hist_priv_kernel(const int* __restrict__ pred, const int* __restrict__ gt,
                      unsigned int* __restrict__ partial, int n4, int n) {
    __shared__ unsigned int h[NWORDS];  // 128 KB
    const int t = threadIdx.x;
    #pragma unroll
    for (int i = t; i < NWORDS; i += HIST_THREADS) h[i] = 0u;
    __syncthreads();

    const vint4* p4 = (const vint4*)pred;
    const vint4* g4 = (const vint4*)gt;
    const int stride = HIST_BLOCKS * HIST_THREADS;
    int i = blockIdx.x * HIST_THREADS + t;
    for (; i + 3 * stride < n4; i += 4 * stride) {
        vint4 pa = __builtin_nontemporal_load(&p4[i]);
        vint4 ga = __builtin_nontemporal_load(&g4[i]);
        vint4 pb = __builtin_nontemporal_load(&p4[i + stride]);
        vint4 gb = __builtin_nontemporal_load(&g4[i + stride]);
        vint4 pc = __builtin_nontemporal_load(&p4[i + 2 * stride]);
        vint4 gc = __builtin_nontemporal_load(&g4[i + 2 * stride]);
        vint4 pd = __builtin_nontemporal_load(&p4[i + 3 * stride]);
        vint4 gd = __builtin_nontemporal_load(&g4[i + 3 * stride]);
        int b;
        b = (ga.x << 8) | pa.x; atomicAdd(&h[b >> 1], 1u << ((b & 1) << 4));
        b = (ga.y << 8) | pa.y; atomicAdd(&h[b >> 1], 1u << ((b & 1) << 4));
        b = (ga.z << 8) | pa.z; atomicAdd(&h[b >> 1], 1u << ((b & 1) << 4));
        b = (ga.w << 8) | pa.w; atomicAdd(&h[b >> 1], 1u << ((b & 1) << 4));
        b = (gb.x << 8) | pb.x; atomicAdd(&h[b >> 1], 1u << ((b & 1) << 4));
        b = (gb.y << 8) | pb.y; atomicAdd(&h[b >> 1], 1u << ((b & 1) << 4));
        b = (gb.z << 8) | pb.z; atomicAdd(&h[b >> 1], 1u << ((b & 1) << 4));
        b = (gb.w << 8) | pb.w; atomicAdd(&h[b >> 1], 1u << ((b & 1) << 4));
        b = (gc.x << 8) | pc.x; atomicAdd(&h[b >> 1], 1u << ((b & 1) << 4));
        b = (gc.y << 8) | pc.y; atomicAdd(&h[b >> 1], 1u << ((b & 1) << 4));
        b = (gc.z << 8) | pc.z; atomicAdd(&h[b >> 1], 1u << ((b & 1) << 4));
        b = (gc.w << 8) | pc.w; atomicAdd(&h[b >> 1], 1u << ((b & 1) << 4));
        b = (gd.x << 8) | pd.x; atomicAdd(&h[b >> 1], 1u << ((b & 1) << 4));
        b = (gd.y << 8) | pd.y; atomicAdd(&h[b >> 1], 1u << ((b & 1) << 4));
        b = (gd.z << 8) | pd.z; atomicAdd(&h[b >> 1], 1u << ((b & 1) << 4));
        b = (gd.w << 8) | pd.w; atomicAdd(&h[b >> 1], 1u << ((b & 1) << 4));
    }
    for (; i < n4; i += stride) {
        vint4 p = p4[i];
        vint4 g = g4[i];
        int b;
        b = (g.x << 8) | p.x; atomicAdd(&h[b >> 1], 1u << ((b & 1) << 4));
        b = (g.y << 8) | p.y; atomicAdd(&h[b >> 1], 1u << ((b & 1) << 4));
        b = (g.z << 8) | p.z; atomicAdd(&h[b >> 1], 1u << ((b & 1) << 4));
        b = (g.w << 8) | p.w; atomicAdd(&h[b >> 1], 1u << ((b & 1) << 4));
    }
    if (blockIdx.x == 0 && t == 0) {  // n%4 tail — dead for 4096x4096
        for (int j = n4 * 4; j < n; ++j) {
            int b = (gt[j] << 8) | pred[j];
            atomicAdd(&h[b >> 1], 1u << ((b & 1) << 4));
        }
    }
    __syncthreads();
    uint4* dst = (uint4*)(partial + (size_t)blockIdx.x * NWORDS);
    const uint4* src = (const uint4*)h;
    #pragma unroll
    for (int j = t; j < NQUADS; j += HIST_THREADS) dst[j] = src[j];
}

// ---------------- reduce: 256 blocks, block r owns row r of C ---------------
// Sums the 256 packed partials for its 256 bins, writes C row, and fuses the
// row-side analysis: gt_size (full row sum incl. background col), pair count
// over Cnz, majority match (at most one col can satisfy 2*v > gt_size).
// meta layout: [0]=gt_size [1]=row_pairs [2]=best_p [3]=inter [4]=has, each x256.
__global__ __launch_bounds__(256)
void reduce_kernel(const unsigned int* __restrict__ partial, int* __restrict__ C,
                   int* __restrict__ meta) {
    __shared__ int acc[256];
    __shared__ int red[4], redp[4];
    __shared__ int s_gs, s_rp, s_best, s_inter;
    const int t = threadIdx.x;
    const int r = blockIdx.x;
    acc[t] = 0;
    if (t == 0) { s_best = 0; s_inter = 0; }
    __syncthreads();

    const int qlocal = t & 31;            // quad within row (32 quads = 256 bins)
    const int q = r * 32 + qlocal;        // global quad index
    const int pg = t >> 5;                // partial group 0..7 (32 partials each)
    const uint4* p4 = (const uint4*)partial;
    int s0 = 0, s1 = 0, s2 = 0, s3 = 0, s4 = 0, s5 = 0, s6 = 0, s7 = 0;
    #pragma unroll 8
    for (int k = 0; k < 32; ++k) {
        uint4 v = p4[(size_t)(pg * 32 + k) * NQUADS + q];
        s0 += (int)(v.x & 0xFFFFu); s1 += (int)(v.x >> 16);
        s2 += (int)(v.y & 0xFFFFu); s3 += (int)(v.y >> 16);
        s4 += (int)(v.z & 0xFFFFu); s5 += (int)(v.z >> 16);
        s6 += (int)(v.w & 0xFFFFu); s7 += (int)(v.w >> 16);
    }
    const int cb = qlocal * 8;
    atomicAdd(&acc[cb + 0], s0); atomicAdd(&acc[cb + 1], s1);
    atomicAdd(&acc[cb + 2], s2); atomicAdd(&acc[cb + 3], s3);
    atomicAdd(&acc[cb + 4], s4); atomicAdd(&acc[cb + 5], s5);
    atomicAdd(&acc[cb + 6], s6); atomicAdd(&acc[cb + 7], s7);
    __syncthreads();

    const int v = acc[t];                 // this row's value at col t
    if (t < 64) ((int4*)(C + r * LBL))[t] = ((const int4*)acc)[t];

    // wave + cross-wave reduction: row sum, Cnz pair count
    int ssum = v;
    int pcnt = (r >= 1 && t >= 1 && v > 0) ? 1 : 0;
    #pragma unroll
    for (int m = 32; m >= 1; m >>= 1) {
        ssum += __shfl_xor(ssum, m);
        pcnt += __shfl_xor(pcnt, m);
    }
    if ((t & 63) == 0) { red[t >> 6] = ssum; redp[t >> 6] = pcnt; }
    __syncthreads();
    if (t == 0) {
        s_gs = red[0] + red[1] + red[2] + red[3];
        s_rp = redp[0] + redp[1] + redp[2] + redp[3];
    }
    __syncthreads();
    const int gs = s_gs;
    // at most one col can satisfy 2v > gs (two would sum past gs) -> plain store
    if (r >= 1 && t >= 1 && 2 * v > gs) { s_best = t; s_inter = v; }
    __syncthreads();
    if (t == 0) {
        meta[0 * LBL + r] = gs;
        meta[1 * LBL + r] = s_rp;
        meta[2 * LBL + r] = s_best;
        meta[3 * LBL + r] = s_inter;
        meta[4 * LBL + r] = (s_best > 0) ? 1 : 0;
    }
}

// ---------------- finalize: column pass + tallies + greedy ------------------
__global__ __launch_bounds__(1024)
void finalize_kernel(const int* __restrict__ C, const int* __restrict__ meta,
                     float* __restrict__ out) {
    __shared__ int colsum[1024], colcnt4[1024];
    __shared__ int pred_size[LBL], colcnt[LBL];
    __shared__ unsigned char used_s[LBL];
    __shared__ int s_ngt, s_npred, s_pairs, s_ea;
    const int t = threadIdx.x;
    if (t == 0) { s_ngt = 0; s_npred = 0; s_pairs = 0; s_ea = 0; }
    if (t < LBL) used_s[t] = 0;

    const int c = t & 255, qg = t >> 8;   // 4 thread-groups of 64 rows each
    int cs = 0, cc = 0;
    #pragma unroll 8
    for (int g0 = 0; g0 < 64; ++g0) {
        int row = qg * 64 + g0;
        int v = C[row * LBL + c];         // coalesced across c
        cs += v;
        cc += (row >= 1 && c >= 1 && v > 0) ? 1 : 0;
    }
    colsum[t] = cs;
    colcnt4[t] = cc;
    __syncthreads();
    if (t < LBL) {
        pred_size[t] = colsum[t] + colsum[256 + t] + colsum[512 + t] + colsum[768 + t];
        colcnt[t]   = colcnt4[t] + colcnt4[256 + t] + colcnt4[512 + t] + colcnt4[768 + t];
    }
    __syncthreads();
    if (t >= 1 && t < LBL) {
        if (meta[0 * LBL + t] > 0) atomicAdd(&s_ngt, 1);
        if (pred_size[t] > 0) atomicAdd(&s_npred, 1);
        if (colcnt[t] > 1) atomicAdd(&s_ea, 1);
        int rp = meta[1 * LBL + t];
        if (rp) atomicAdd(&s_pairs, rp);
    }
    __syncthreads();

    if (t == 0) {
        const int num_gt = s_ngt, num_pred = s_npred, pairs = s_pairs, ea = s_ea;
        int tp = 0;
        float seg_sum = 0.0f;
        // greedy matching in ascending gt-label order; a pred may match once
        for (int gl = 1; gl < LBL; ++gl) {
            if (meta[4 * LBL + gl]) {
                int pl = meta[2 * LBL + gl];
                if (!used_s[pl]) {
                    int uni = meta[0 * LBL + gl] + pred_size[pl] - meta[3 * LBL + gl];
                    if (uni < 1) uni = 1;
                    seg_sum += (float)meta[3 * LBL + gl] / (float)uni;
                    used_s[pl] = 1;
                    tp++;
                }
            }
        }
        float ng = (float)(num_gt >= 1 ? num_gt : 1);
        float seg = seg_sum / ng;
        int ns = pairs - tp;
        int fn = num_gt - tp;
        int fp_ = num_pred - tp;
        float det = 1.0f - (float)(fp_ + fn + ns + ea) / ng;
        bool both_empty = (num_gt == 0) && (num_pred == 0);
        bool any_empty = (num_gt == 0) || (num_pred == 0);
        if (both_empty) { seg = 1.0f; det = 1.0f; }
        else if (any_empty) { seg = 0.0f; det = 0.0f; }
        out[0] = seg;
        out[1] = det;
    }
}

// ---------------- fallback path (tiny ws): direct atomics + full finalize ---
__global__ void hist_atomic_kernel(const int* __restrict__ pred, const int* __restrict__ gt,
                                   int* __restrict__ C, int n4, int n) {
    int idx = blockIdx.x * blockDim.x + threadIdx.x;
    int stride = gridDim.x * blockDim.x;
    const vint4* p4 = (const vint4*)pred;
    const vint4* g4 = (const vint4*)gt;
    for (int i = idx; i < n4; i += stride) {
        vint4 p = p4[i];
        vint4 g = g4[i];
        atomicAdd(&C[(g.x << 8) + p.x], 1);
        atomicAdd(&C[(g.y << 8) + p.y], 1);
        atomicAdd(&C[(g.z << 8) + p.z], 1);
        atomicAdd(&C[(g.w << 8) + p.w], 1);
    }
    if (idx == 0)
        for (int i = n4 * 4; i < n; ++i) atomicAdd(&C[(gt[i] << 8) + pred[i]], 1);
}

__global__ __launch_bounds__(1024)
void finalize_full_kernel(const int* __restrict__ C, float* __restrict__ out) {
    __shared__ int scratch[1024];
    __shared__ int gt_size[LBL], pred_size[LBL];
    __shared__ int best_p[LBL], inter_s[LBL], colcnt[LBL];
    __shared__ unsigned char has_s[LBL], used_s[LBL];
    __shared__ int s_pairs, s_ngt, s_npred, s_ea;
    const int t = threadIdx.x;
    if (t == 0) { s_pairs = 0; s_ngt = 0; s_npred = 0; s_ea = 0; }
    if (t < LBL) { best_p[t] = 0; inter_s[t] = 0; colcnt[t] = 0; has_s[t] = 0; used_s[t] = 0; }
    const int4* C4 = (const int4*)C;
    const int r = t >> 2, q = t & 3;
    int s = 0;
    #pragma unroll
    for (int j = 0; j < 16; ++j) {
        int4 v = C4[r * 64 + q * 16 + j];
        s += v.x + v.y + v.z + v.w;
    }
    scratch[t] = s;
    __syncthreads();
    if (t < LBL)
        gt_size[t] = scratch[4 * t] + scratch[4 * t + 1] + scratch[4 * t + 2] + scratch[4 * t + 3];
    __syncthreads();
    {
        const int c = t & 255, q2 = t >> 8;
        int cs = 0, cc = 0;
        #pragma unroll 8
        for (int g0 = 0; g0 < 64; ++g0) {
            int row = q2 * 64 + g0;
            int v = C[row * LBL + c];
            cs += v;
            cc += (row >= 1 && c >= 1 && v > 0) ? 1 : 0;
        }
        scratch[t] = cs;
        if (cc) atomicAdd(&colcnt[c], cc);
    }
    if (r >= 1) {
        const int gs = gt_size[r];
        int rp = 0;
        #pragma unroll
        for (int j = 0; j < 16; ++j) {
            int4 v = C4[r * 64 + q * 16 + j];
            int cb = q * 64 + 4 * j;
            if (cb >= 1) {
                if (v.x > 0) rp++;
                if (2 * v.x > gs) { has_s[r] = 1; best_p[r] = cb; inter_s[r] = v.x; }
            }
            if (v.y > 0) rp++;
            if (2 * v.y > gs) { has_s[r] = 1; best_p[r] = cb + 1; inter_s[r] = v.y; }
            if (v.z > 0) rp++;
            if (2 * v.z > gs) { has_s[r] = 1; best_p[r] = cb + 2; inter_s[r] = v.z; }
            if (v.w > 0) rp++;
            if (2 * v.w > gs) { has_s[r] = 1; best_p[r] = cb + 3; inter_s[r] = v.w; }
        }
        if (rp) atomicAdd(&s_pairs, rp);
    }
    __syncthreads();
    if (t < LBL)
        pred_size[t] = scratch[t] + scratch[256 + t] + scratch[512 + t] + scratch[768 + t];
    __syncthreads();
    if (t >= 1 && t < LBL) {
        if (gt_size[t] > 0) atomicAdd(&s_ngt, 1);
        if (pred_size[t] > 0) atomicAdd(&s_npred, 1);
        if (colcnt[t] > 1) atomicAdd(&s_ea, 1);
    }
    __syncthreads();
    if (t == 0) {
        const int num_gt = s_ngt, num_pred = s_npred, pairs = s_pairs, ea = s_ea;
        int tp = 0;
        float seg_sum = 0.0f;
        for (int gl = 1; gl < LBL; ++gl) {
            if (has_s[gl]) {
                int pl = best_p[gl];
                if (!used_s[pl]) {
                    int uni = gt_size[gl] + pred_size[pl] - inter_s[gl];
                    if (uni < 1) uni = 1;
                    seg_sum += (float)inter_s[gl] / (float)uni;
                    used_s[pl] = 1;
                    tp++;
                }
            }
        }
        float ng = (float)(num_gt >= 1 ? num_gt : 1);
        float seg = seg_sum / ng;
        int ns = pairs - tp;
        int fn = num_gt - tp;
        int fp_ = num_pred - tp;
        float det = 1.0f - (float)(fp_ + fn + ns + ea) / ng;
        bool both_empty = (num_gt == 0) && (num_pred == 0);
        bool any_empty = (num_gt == 0) || (num_pred == 0);
        if (both_empty) { seg = 1.0f; det = 1.0f; }
        else if (any_empty) { seg = 0.0f; det = 0.0f; }
        out[0] = seg;
        out[1] = det;
    }
}

extern "C" void kernel_launch(void* const* d_in, const int* in_sizes, int n_in,
                              void* d_out, int out_size, void* d_ws, size_t ws_size,
                              hipStream_t stream) {
    const int* pred = (const int*)d_in[0];
    const int* gt = (const int*)d_in[1];
    float* out = (float*)d_out;
    const int n = in_sizes[0];
    const int n4 = n / 4;

    const size_t part_bytes = (size_t)HIST_BLOCKS * NWORDS * sizeof(unsigned int);  // 32 MB
    const size_t c_bytes = (size_t)NBINS * sizeof(int);                             // 256 KB
    const size_t meta_bytes = 5 * LBL * sizeof(int);                                // 5 KB
    if (ws_size >= part_bytes + c_bytes + meta_bytes) {
        unsigned int* partial = (unsigned int*)d_ws;
        int* C = (int*)((char*)d_ws + part_bytes);
        int* meta = (int*)((char*)d_ws + part_bytes + c_bytes);
        hist_priv_kernel<<<HIST_BLOCKS, HIST_THREADS, 0, stream>>>(pred, gt, partial, n4, n);
        reduce_kernel<<<LBL, 256, 0, stream>>>(partial, C, meta);
        finalize_kernel<<<1, 1024, 0, stream>>>(C, meta, out);
    } else {
        int* C = (int*)d_ws;
        (void)hipMemsetAsync(C, 0, c_bytes, stream);
        hist_atomic_kernel<<<2048, 256, 0, stream>>>(pred, gt, C, n4, n);
        finalize_full_kernel<<<1, 1024, 0, stream>>>(C, out);
    }
}